// Round 1
// baseline (1912.337 us; speedup 1.0000x reference)
//
#include <hip/hip_runtime.h>
#include <math.h>

#define B_N 262144
#define K_N 100
#define D_N 384
#define EPS 1e-8f
#define MOM 0.95f
#define SEG_S 8

// workspace byte offsets
#define OFF_CN    0          // K*D f32 = 153600
#define OFF_NC64  153600     // K f64   = 800
#define OFF_CNT   154400     // K i32
#define OFF_OFFS  154800     // K i32
#define OFF_CUR   155200     // K i32
#define OFF_IDX   155648     // B u32   = 1048576
#define OFF_PART  1204224    // K*SEG_S*D f64 = 2457600  (total 3661824 B)

// ---- normalize centroids: c_n = c / max(||c||, eps); store clamped fp64 norm ----
__global__ void k_norm_c(const float* __restrict__ c, float* __restrict__ c_n,
                         double* __restrict__ nc64) {
    int k = blockIdx.x;
    int t = threadIdx.x;  // 128 threads
    const float* row = c + (size_t)k * D_N;
    double ss = 0.0;
    for (int d = t; d < D_N; d += 128) { double v = row[d]; ss += v * v; }
    __shared__ double red[2];
    for (int o = 32; o > 0; o >>= 1) ss += __shfl_down(ss, o);
    if ((t & 63) == 0) red[t >> 6] = ss;
    __syncthreads();
    double nc = fmax(sqrt(red[0] + red[1]), (double)EPS);
    if (t == 0) nc64[k] = nc;
    float inv = (float)(1.0 / nc);
    for (int d = t; d < D_N; d += 128) c_n[(size_t)k * D_N + d] = row[d] * inv;
}

__global__ void k_zero(int* cnt, int* cur) {
    int t = threadIdx.x;
    if (t < K_N) { cnt[t] = 0; cur[t] = 0; }
}

// ---- main: sims + max/argmax (+fp64 tie refinement) + novelty + histogram ----
__global__ __launch_bounds__(256) void k_main(
    const float* __restrict__ e, const float* __restrict__ c_n,
    const float* __restrict__ c_raw, const double* __restrict__ nc64,
    float* __restrict__ out_nov, float* __restrict__ out_cls,
    int* __restrict__ cnt) {
    const int b = blockIdx.x * 256 + threadIdx.x;
    const float* __restrict__ row = e + (size_t)b * D_N;
    float acc[K_N];
#pragma unroll
    for (int k = 0; k < K_N; k++) acc[k] = 0.f;
    float ss = 0.f;

    for (int d0 = 0; d0 < D_N; d0 += 16) {
        const float4 e0 = *(const float4*)(row + d0);
        const float4 e1 = *(const float4*)(row + d0 + 4);
        const float4 e2 = *(const float4*)(row + d0 + 8);
        const float4 e3 = *(const float4*)(row + d0 + 12);
        ss += e0.x * e0.x + e0.y * e0.y + e0.z * e0.z + e0.w * e0.w
            + e1.x * e1.x + e1.y * e1.y + e1.z * e1.z + e1.w * e1.w
            + e2.x * e2.x + e2.y * e2.y + e2.z * e2.z + e2.w * e2.w
            + e3.x * e3.x + e3.y * e3.y + e3.z * e3.z + e3.w * e3.w;
#pragma unroll
        for (int k = 0; k < K_N; k++) {
            const float* cp = c_n + (size_t)k * D_N + d0;   // uniform addr -> s_load
            const float4 c0 = *(const float4*)(cp);
            const float4 c1 = *(const float4*)(cp + 4);
            const float4 c2 = *(const float4*)(cp + 8);
            const float4 c3 = *(const float4*)(cp + 12);
            float a = acc[k];
            a = fmaf(e0.x, c0.x, a); a = fmaf(e0.y, c0.y, a);
            a = fmaf(e0.z, c0.z, a); a = fmaf(e0.w, c0.w, a);
            a = fmaf(e1.x, c1.x, a); a = fmaf(e1.y, c1.y, a);
            a = fmaf(e1.z, c1.z, a); a = fmaf(e1.w, c1.w, a);
            a = fmaf(e2.x, c2.x, a); a = fmaf(e2.y, c2.y, a);
            a = fmaf(e2.z, c2.z, a); a = fmaf(e2.w, c2.w, a);
            a = fmaf(e3.x, c3.x, a); a = fmaf(e3.y, c3.y, a);
            a = fmaf(e3.z, c3.z, a); a = fmaf(e3.w, c3.w, a);
            acc[k] = a;
        }
    }

    // max / argmax / second max
    float best = acc[0]; int bi = 0;
    float second = -1e30f; int si = 1;
#pragma unroll
    for (int k = 1; k < K_N; k++) {
        float v = acc[k];
        if (v > best) { second = best; si = bi; best = v; bi = k; }
        else if (v > second) { second = v; si = k; }
    }

    // fp64 refinement of argmax when top-2 nearly tie (rare)
    if (best - second < 2e-3f) {
        const float* ca = c_raw + (size_t)bi * D_N;
        const float* cb = c_raw + (size_t)si * D_N;
        double s1 = 0.0, s2 = 0.0;
        for (int d = 0; d < D_N; d++) {
            double ev = (double)row[d];
            s1 += ev * (double)ca[d];
            s2 += ev * (double)cb[d];
        }
        double v1 = s1 / nc64[bi], v2 = s2 / nc64[si];
        if (v2 > v1 || (v2 == v1 && si < bi)) bi = si;
    }

    float nrm = fmaxf(sqrtf(ss), EPS);
    float msim = best / nrm;
    out_nov[b] = 1.0f - msim * msim;
    out_cls[b] = (float)bi;
    atomicAdd(&cnt[bi], 1);
}

// ---- exclusive prefix of histogram + new_counts output ----
__global__ void k_prefix(const int* __restrict__ cnt, int* __restrict__ offs,
                         const float* __restrict__ counts_in, float* __restrict__ out_cnts) {
    if (threadIdx.x == 0) {
        int r = 0;
        for (int k = 0; k < K_N; k++) { offs[k] = r; r += cnt[k]; }
    }
    int t = threadIdx.x;
    if (t < K_N) out_cnts[t] = counts_in[t] + (float)cnt[t];
}

// ---- scatter row indices into cluster buckets ----
__global__ void k_scatter(const float* __restrict__ cls, const int* __restrict__ offs,
                          int* __restrict__ cur, unsigned* __restrict__ idx_buf) {
    int b = blockIdx.x * 256 + threadIdx.x;
    int k = (int)cls[b];
    int pos = atomicAdd(&cur[k], 1);
    idx_buf[offs[k] + pos] = (unsigned)b;
}

// ---- per-cluster segment sums (fp64 partials, no float atomics) ----
__global__ void k_segsum(const float* __restrict__ e, const unsigned* __restrict__ idx_buf,
                         const int* __restrict__ cnt, const int* __restrict__ offs,
                         double* __restrict__ partial) {
    int k = blockIdx.x, s = blockIdx.y, t = threadIdx.x;  // 384 threads: t = dim
    int n = cnt[k], base = offs[k];
    int i0 = (int)((long long)n * s / SEG_S);
    int i1 = (int)((long long)n * (s + 1) / SEG_S);
    double a = 0.0;
#pragma unroll 4
    for (int i = i0; i < i1; i++) {
        unsigned r = idx_buf[base + i];
        a += (double)e[(size_t)r * D_N + t];
    }
    partial[((size_t)k * SEG_S + s) * D_N + t] = a;
}

// ---- finalize centroids ----
__global__ void k_final(const float* __restrict__ c_raw, const double* __restrict__ partial,
                        const int* __restrict__ cnt, float* __restrict__ out_cent) {
    int idx = blockIdx.x * 256 + threadIdx.x;
    if (idx >= K_N * D_N) return;
    int k = idx / D_N;
    int d = idx - k * D_N;
    double sum = 0.0;
#pragma unroll
    for (int s = 0; s < SEG_S; s++) sum += partial[((size_t)k * SEG_S + s) * D_N + d];
    int n = cnt[k];
    float c0 = c_raw[idx];
    float mean = (float)(sum / (double)(n > 1 ? n : 1));
    out_cent[idx] = (n > 0) ? (MOM * c0 + (1.0f - MOM) * mean) : c0;
}

extern "C" void kernel_launch(void* const* d_in, const int* in_sizes, int n_in,
                              void* d_out, int out_size, void* d_ws, size_t ws_size,
                              hipStream_t stream) {
    const float* emb    = (const float*)d_in[0];
    const float* cen    = (const float*)d_in[1];
    const float* counts = (const float*)d_in[2];
    float* out = (float*)d_out;
    char* ws = (char*)d_ws;

    float*    c_n     = (float*)(ws + OFF_CN);
    double*   nc64    = (double*)(ws + OFF_NC64);
    int*      cnt     = (int*)(ws + OFF_CNT);
    int*      offs    = (int*)(ws + OFF_OFFS);
    int*      cur     = (int*)(ws + OFF_CUR);
    unsigned* idx_buf = (unsigned*)(ws + OFF_IDX);
    double*   partial = (double*)(ws + OFF_PART);

    float* out_nov  = out;
    float* out_cls  = out + B_N;
    float* out_cent = out + 2 * B_N;
    float* out_cnts = out + 2 * B_N + K_N * D_N;

    k_norm_c<<<K_N, 128, 0, stream>>>(cen, c_n, nc64);
    k_zero<<<1, 128, 0, stream>>>(cnt, cur);
    k_main<<<B_N / 256, 256, 0, stream>>>(emb, c_n, cen, nc64, out_nov, out_cls, cnt);
    k_prefix<<<1, 128, 0, stream>>>(cnt, offs, counts, out_cnts);
    k_scatter<<<B_N / 256, 256, 0, stream>>>(out_cls, offs, cur, idx_buf);
    k_segsum<<<dim3(K_N, SEG_S), 384, 0, stream>>>(emb, idx_buf, cnt, offs, partial);
    k_final<<<(K_N * D_N + 255) / 256, 256, 0, stream>>>(cen, partial, cnt, out_cent);
}

// Round 2
// 1019.447 us; speedup vs baseline: 1.8759x; 1.8759x over previous
//
#include <hip/hip_runtime.h>
#include <math.h>

#define B_N 262144
#define K_N 100
#define D_N 384
#define EPS 1e-8f
#define MOM 0.95f
#define KT  50            // K-tile: 2 passes of 50 clusters -> no VGPR spill
#define SEG_MAX 32

// workspace byte offsets
#define OFF_CN    0          // K*D f32 = 153600
#define OFF_NC64  153600     // K f64   = 800
#define OFF_CNT   154400     // K i32
#define OFF_OFFS  154800     // K i32
#define OFF_CUR   155200     // K i32
#define OFF_IDX   155648     // B u32   = 1048576
#define OFF_PART  1204224    // K*seg*D f64 (seg<=32 -> 9830400 B)

// ---- normalize centroids: c_n = c / max(||c||, eps); store clamped fp64 norm ----
__global__ void k_norm_c(const float* __restrict__ c, float* __restrict__ c_n,
                         double* __restrict__ nc64) {
    int k = blockIdx.x;
    int t = threadIdx.x;  // 128 threads
    const float* row = c + (size_t)k * D_N;
    double ss = 0.0;
    for (int d = t; d < D_N; d += 128) { double v = row[d]; ss += v * v; }
    __shared__ double red[2];
    for (int o = 32; o > 0; o >>= 1) ss += __shfl_down(ss, o);
    if ((t & 63) == 0) red[t >> 6] = ss;
    __syncthreads();
    double nc = fmax(sqrt(red[0] + red[1]), (double)EPS);
    if (t == 0) nc64[k] = nc;
    float inv = (float)(1.0 / nc);
    for (int d = t; d < D_N; d += 128) c_n[(size_t)k * D_N + d] = row[d] * inv;
}

__global__ void k_zero(int* cnt) {
    int t = threadIdx.x;
    if (t < K_N) cnt[t] = 0;
}

// ---- one K-tile of the sims GEMV: acc[KT] += e-row . c_n[kbase+k,:] ----
template<bool WITH_SS>
__device__ __forceinline__ void sims_tile(const float* __restrict__ row,
                                          const float* __restrict__ cbase,
                                          float* __restrict__ acc, float& ss) {
#pragma unroll
    for (int k = 0; k < KT; k++) acc[k] = 0.f;
    for (int d0 = 0; d0 < D_N; d0 += 8) {
        const float4 e0 = *(const float4*)(row + d0);
        const float4 e1 = *(const float4*)(row + d0 + 4);
        if (WITH_SS) {
            ss += e0.x * e0.x + e0.y * e0.y + e0.z * e0.z + e0.w * e0.w
                + e1.x * e1.x + e1.y * e1.y + e1.z * e1.z + e1.w * e1.w;
        }
#pragma unroll
        for (int k = 0; k < KT; k++) {
            const float* cp = cbase + (size_t)k * D_N + d0;   // wave-uniform -> s_load
            const float4 c0 = *(const float4*)(cp);
            const float4 c1 = *(const float4*)(cp + 4);
            float a = acc[k];
            a = fmaf(e0.x, c0.x, a); a = fmaf(e0.y, c0.y, a);
            a = fmaf(e0.z, c0.z, a); a = fmaf(e0.w, c0.w, a);
            a = fmaf(e1.x, c1.x, a); a = fmaf(e1.y, c1.y, a);
            a = fmaf(e1.z, c1.z, a); a = fmaf(e1.w, c1.w, a);
            acc[k] = a;
        }
    }
}

// ---- main: sims + max/argmax (+fp64 tie refinement) + novelty + block histogram ----
__global__ __launch_bounds__(256) void k_main(
    const float* __restrict__ e, const float* __restrict__ c_n,
    const float* __restrict__ c_raw, const double* __restrict__ nc64,
    float* __restrict__ out_nov, float* __restrict__ out_cls,
    int* __restrict__ cnt) {
    __shared__ int h[K_N];
    const int t = threadIdx.x;
    if (t < K_N) h[t] = 0;
    __syncthreads();

    const int b = blockIdx.x * 256 + t;
    const float* __restrict__ row = e + (size_t)b * D_N;
    float best = -1e30f, second = -1e30f;
    int bi = 0, si = 0;
    float ss = 0.f;
    float acc[KT];

    // tile 0: clusters [0,50)
    sims_tile<true>(row, c_n, acc, ss);
#pragma unroll
    for (int k = 0; k < KT; k++) {
        float v = acc[k];
        if (v > best) { second = best; si = bi; best = v; bi = k; }
        else if (v > second) { second = v; si = k; }
    }
    // tile 1: clusters [50,100)
    sims_tile<false>(row, c_n + (size_t)KT * D_N, acc, ss);
#pragma unroll
    for (int k = 0; k < KT; k++) {
        float v = acc[k]; int kk = KT + k;
        if (v > best) { second = best; si = bi; best = v; bi = kk; }
        else if (v > second) { second = v; si = kk; }
    }

    // fp64 refinement of argmax when top-2 nearly tie (~0.5% of rows)
    if (best - second < 2e-3f) {
        const float* ca = c_raw + (size_t)bi * D_N;
        const float* cb = c_raw + (size_t)si * D_N;
        double s1 = 0.0, s2 = 0.0;
        for (int d = 0; d < D_N; d++) {
            double ev = (double)row[d];
            s1 += ev * (double)ca[d];
            s2 += ev * (double)cb[d];
        }
        double v1 = s1 / nc64[bi], v2 = s2 / nc64[si];
        if (v2 > v1 || (v2 == v1 && si < bi)) bi = si;
    }

    float nrm = fmaxf(sqrtf(ss), EPS);
    float msim = best / nrm;
    out_nov[b] = 1.0f - msim * msim;
    out_cls[b] = (float)bi;

    atomicAdd(&h[bi], 1);            // LDS atomic (fast, distributed)
    __syncthreads();
    if (t < K_N && h[t] > 0) atomicAdd(&cnt[t], h[t]);   // <=100 global atomics/block
}

// ---- exclusive prefix of histogram + init cur + new_counts output ----
__global__ void k_prefix(const int* __restrict__ cnt, int* __restrict__ offs,
                         int* __restrict__ cur,
                         const float* __restrict__ counts_in, float* __restrict__ out_cnts) {
    if (threadIdx.x == 0) {
        int r = 0;
        for (int k = 0; k < K_N; k++) { offs[k] = r; cur[k] = r; r += cnt[k]; }
    }
    int t = threadIdx.x;
    if (t < K_N) out_cnts[t] = counts_in[t] + (float)cnt[t];
}

// ---- scatter row indices into cluster buckets (block-aggregated reservations) ----
__global__ void k_scatter(const float* __restrict__ cls, int* __restrict__ cur,
                          unsigned* __restrict__ idx_buf) {
    __shared__ int h[K_N];
    __shared__ int basek[K_N];
    int t = threadIdx.x;
    if (t < K_N) h[t] = 0;
    __syncthreads();
    int b = blockIdx.x * 256 + t;
    int k = (int)cls[b];
    int lr = atomicAdd(&h[k], 1);               // LDS: local rank within block
    __syncthreads();
    if (t < K_N && h[t] > 0) basek[t] = atomicAdd(&cur[t], h[t]);  // reserve range
    __syncthreads();
    idx_buf[basek[k] + lr] = (unsigned)b;
}

// ---- per-cluster segment sums (fp64 partials, 8-deep row prefetch) ----
__global__ void k_segsum(const float* __restrict__ e, const unsigned* __restrict__ idx_buf,
                         const int* __restrict__ cnt, const int* __restrict__ offs,
                         double* __restrict__ partial, int seg) {
    int k = blockIdx.x, s = blockIdx.y, t = threadIdx.x;  // 384 threads: t = dim
    int n = cnt[k], base = offs[k];
    int i0 = (int)((long long)n * s / seg);
    int i1 = (int)((long long)n * (s + 1) / seg);
    double a = 0.0;
    int i = i0;
    for (; i + 8 <= i1; i += 8) {
        unsigned r0 = idx_buf[base + i + 0], r1 = idx_buf[base + i + 1];
        unsigned r2 = idx_buf[base + i + 2], r3 = idx_buf[base + i + 3];
        unsigned r4 = idx_buf[base + i + 4], r5 = idx_buf[base + i + 5];
        unsigned r6 = idx_buf[base + i + 6], r7 = idx_buf[base + i + 7];
        float f0 = e[(size_t)r0 * D_N + t], f1 = e[(size_t)r1 * D_N + t];
        float f2 = e[(size_t)r2 * D_N + t], f3 = e[(size_t)r3 * D_N + t];
        float f4 = e[(size_t)r4 * D_N + t], f5 = e[(size_t)r5 * D_N + t];
        float f6 = e[(size_t)r6 * D_N + t], f7 = e[(size_t)r7 * D_N + t];
        a += (double)f0; a += (double)f1; a += (double)f2; a += (double)f3;
        a += (double)f4; a += (double)f5; a += (double)f6; a += (double)f7;
    }
    for (; i < i1; ++i)
        a += (double)e[(size_t)idx_buf[base + i] * D_N + t];
    partial[((size_t)(k * seg + s)) * D_N + t] = a;
}

// ---- finalize centroids ----
__global__ void k_final(const float* __restrict__ c_raw, const double* __restrict__ partial,
                        const int* __restrict__ cnt, float* __restrict__ out_cent, int seg) {
    int idx = blockIdx.x * 256 + threadIdx.x;
    if (idx >= K_N * D_N) return;
    int k = idx / D_N;
    int d = idx - k * D_N;
    double sum = 0.0;
    for (int s = 0; s < seg; s++) sum += partial[((size_t)(k * seg + s)) * D_N + d];
    int n = cnt[k];
    float c0 = c_raw[idx];
    float mean = (float)(sum / (double)(n > 1 ? n : 1));
    out_cent[idx] = (n > 0) ? (MOM * c0 + (1.0f - MOM) * mean) : c0;
}

extern "C" void kernel_launch(void* const* d_in, const int* in_sizes, int n_in,
                              void* d_out, int out_size, void* d_ws, size_t ws_size,
                              hipStream_t stream) {
    const float* emb    = (const float*)d_in[0];
    const float* cen    = (const float*)d_in[1];
    const float* counts = (const float*)d_in[2];
    float* out = (float*)d_out;
    char* ws = (char*)d_ws;

    float*    c_n     = (float*)(ws + OFF_CN);
    double*   nc64    = (double*)(ws + OFF_NC64);
    int*      cnt     = (int*)(ws + OFF_CNT);
    int*      offs    = (int*)(ws + OFF_OFFS);
    int*      cur     = (int*)(ws + OFF_CUR);
    unsigned* idx_buf = (unsigned*)(ws + OFF_IDX);
    double*   partial = (double*)(ws + OFF_PART);

    // pick segment-split factor by available workspace (partial = K*seg*D*8 bytes)
    int seg = SEG_MAX;
    while (seg > 1 && OFF_PART + (size_t)K_N * seg * D_N * 8 > ws_size) seg >>= 1;

    float* out_nov  = out;
    float* out_cls  = out + B_N;
    float* out_cent = out + 2 * B_N;
    float* out_cnts = out + 2 * B_N + K_N * D_N;

    k_norm_c<<<K_N, 128, 0, stream>>>(cen, c_n, nc64);
    k_zero<<<1, 128, 0, stream>>>(cnt);
    k_main<<<B_N / 256, 256, 0, stream>>>(emb, c_n, cen, nc64, out_nov, out_cls, cnt);
    k_prefix<<<1, 128, 0, stream>>>(cnt, offs, cur, counts, out_cnts);
    k_scatter<<<B_N / 256, 256, 0, stream>>>(out_cls, cur, idx_buf);
    k_segsum<<<dim3(K_N, seg), 384, 0, stream>>>(emb, idx_buf, cnt, offs, partial, seg);
    k_final<<<(K_N * D_N + 255) / 256, 256, 0, stream>>>(cen, partial, cnt, out_cent, seg);
}

// Round 3
// 402.358 us; speedup vs baseline: 4.7528x; 2.5337x over previous
//
#include <hip/hip_runtime.h>
#include <math.h>

#define B_N 262144
#define K_N 100
#define NPAD 112
#define D_N 384
#define EPS 1e-8f
#define MOM 0.95f
#define SEG_MAX 32

typedef __attribute__((ext_vector_type(8))) short short8;
typedef __attribute__((ext_vector_type(4))) float f32x4;

// workspace byte offsets
#define OFF_CHI   0          // NPAD*D bf16 = 86016
#define OFF_CLO   86016      // NPAD*D bf16 = 86016
#define OFF_NC64  172032     // K f64 = 800
#define OFF_CNT   172832     // K i32
#define OFF_OFFS  173248     // K i32
#define OFF_CUR   173696     // K i32
#define OFF_FLAGN 174144     // 1 i32 (+pad)
#define OFF_FLAGS 174208     // B u32 = 1048576
#define OFF_IDX   1222784    // B u32 = 1048576
#define OFF_PART  2271360    // K*seg*D f64

// ---- normalize centroids -> bf16 hi/lo split; rows [K_N,NPAD) zeroed ----
__global__ void k_norm_c(const float* __restrict__ c, unsigned short* __restrict__ chi,
                         unsigned short* __restrict__ clo, double* __restrict__ nc64) {
    int k = blockIdx.x;
    int t = threadIdx.x;  // 128
    if (k >= K_N) {
        for (int d = t; d < D_N; d += 128) { chi[k * D_N + d] = 0; clo[k * D_N + d] = 0; }
        return;
    }
    const float* row = c + (size_t)k * D_N;
    double ss = 0.0;
    for (int d = t; d < D_N; d += 128) { double v = row[d]; ss += v * v; }
    __shared__ double red[2];
    for (int o = 32; o > 0; o >>= 1) ss += __shfl_down(ss, o);
    if ((t & 63) == 0) red[t >> 6] = ss;
    __syncthreads();
    double nc = fmax(sqrt(red[0] + red[1]), (double)EPS);
    if (t == 0) nc64[k] = nc;
    float inv = (float)(1.0 / nc);
    for (int d = t; d < D_N; d += 128) {
        float x = row[d] * inv;
        unsigned xb = __float_as_uint(x);
        unsigned hb = xb & 0xffff0000u;
        float lf = x - __uint_as_float(hb);
        chi[k * D_N + d] = (unsigned short)(hb >> 16);
        clo[k * D_N + d] = (unsigned short)(__float_as_uint(lf) >> 16);
    }
}

__global__ void k_zero(int* cnt, int* flagn) {
    int t = threadIdx.x;
    if (t < K_N) cnt[t] = 0;
    if (t == 0) *flagn = 0;
}

// ---- split 8 contiguous floats into bf16 hi/lo fragments + accumulate ss ----
__device__ __forceinline__ void splitA(const float* __restrict__ p,
                                       short8& ah, short8& al, float& ss) {
    float4 x0 = *(const float4*)p;
    float4 x1 = *(const float4*)(p + 4);
    float xs[8] = {x0.x, x0.y, x0.z, x0.w, x1.x, x1.y, x1.z, x1.w};
#pragma unroll
    for (int j = 0; j < 8; j++) {
        float x = xs[j];
        unsigned xb = __float_as_uint(x);
        unsigned hb = xb & 0xffff0000u;
        float lf = x - __uint_as_float(hb);
        ah[j] = (short)(hb >> 16);
        al[j] = (short)(__float_as_uint(lf) >> 16);
        ss = fmaf(x, x, ss);
    }
}

// ---- MFMA sims + max/argmax + novelty + flag near-ties ----
__global__ __launch_bounds__(256) void k_main(
    const float* __restrict__ e, const unsigned short* __restrict__ chi,
    const unsigned short* __restrict__ clo,
    float* __restrict__ out_nov, float* __restrict__ out_cls,
    unsigned* __restrict__ flags, int* __restrict__ flagn) {
    const int t = threadIdx.x;
    const int lane = t & 63;
    const int wid = t >> 6;
    const int l15 = lane & 15;
    const int lg = lane >> 4;                    // k-group 0..3
    const int rowbase = blockIdx.x * 128 + wid * 32;

    f32x4 acc[2][7];
#pragma unroll
    for (int rt = 0; rt < 2; rt++)
#pragma unroll
        for (int nt = 0; nt < 7; nt++) acc[rt][nt] = f32x4{0.f, 0.f, 0.f, 0.f};

    float ss0 = 0.f, ss1 = 0.f;
    const float* a0p = e + (size_t)(rowbase + l15) * D_N + lg * 8;
    const float* a1p = a0p + (size_t)16 * D_N;
    const unsigned short* bhp = chi + (size_t)l15 * D_N + lg * 8;
    const unsigned short* blp = clo + (size_t)l15 * D_N + lg * 8;

    for (int kk = 0; kk < 12; kk++) {
        const int ko = kk * 32;
        short8 bh[7], bl[7];
#pragma unroll
        for (int nt = 0; nt < 7; nt++) {
            bh[nt] = *(const short8*)(bhp + (size_t)nt * 16 * D_N + ko);
            bl[nt] = *(const short8*)(blp + (size_t)nt * 16 * D_N + ko);
        }
        short8 ah0, al0, ah1, al1;
        splitA(a0p + ko, ah0, al0, ss0);
        splitA(a1p + ko, ah1, al1, ss1);
#pragma unroll
        for (int nt = 0; nt < 7; nt++) {
            acc[0][nt] = __builtin_amdgcn_mfma_f32_16x16x32_bf16(ah0, bh[nt], acc[0][nt], 0, 0, 0);
            acc[0][nt] = __builtin_amdgcn_mfma_f32_16x16x32_bf16(al0, bh[nt], acc[0][nt], 0, 0, 0);
            acc[0][nt] = __builtin_amdgcn_mfma_f32_16x16x32_bf16(ah0, bl[nt], acc[0][nt], 0, 0, 0);
            acc[1][nt] = __builtin_amdgcn_mfma_f32_16x16x32_bf16(ah1, bh[nt], acc[1][nt], 0, 0, 0);
            acc[1][nt] = __builtin_amdgcn_mfma_f32_16x16x32_bf16(al1, bh[nt], acc[1][nt], 0, 0, 0);
            acc[1][nt] = __builtin_amdgcn_mfma_f32_16x16x32_bf16(ah1, bl[nt], acc[1][nt], 0, 0, 0);
        }
    }

    // row sum-of-squares: lanes sharing l15 hold disjoint k-chunks
    ss0 += __shfl_xor(ss0, 16); ss0 += __shfl_xor(ss0, 32);
    ss1 += __shfl_xor(ss1, 16); ss1 += __shfl_xor(ss1, 32);
    const int rl = lg * 4 + (l15 & 3);           // row this lane will handle
    float ssr0 = __shfl(ss0, rl);                // all lanes execute (no divergence)
    float ssr1 = __shfl(ss1, rl);

#pragma unroll
    for (int rt = 0; rt < 2; rt++) {
        float b0 = -3e38f, b1 = -3e38f, b2 = -3e38f, b3 = -3e38f;
        float s0 = -3e38f, s1 = -3e38f, s2 = -3e38f, s3 = -3e38f;
        int i0 = 0, i1 = 0, i2 = 0, i3 = 0, j0 = 0, j1 = 0, j2 = 0, j3 = 0;
#pragma unroll
        for (int nt = 0; nt < 7; nt++) {
            int cl = nt * 16 + l15;
            bool valid = cl < K_N;
            float v;
            v = valid ? acc[rt][nt][0] : -3e38f;
            if (v > b0) { s0 = b0; j0 = i0; b0 = v; i0 = cl; } else if (v > s0) { s0 = v; j0 = cl; }
            v = valid ? acc[rt][nt][1] : -3e38f;
            if (v > b1) { s1 = b1; j1 = i1; b1 = v; i1 = cl; } else if (v > s1) { s1 = v; j1 = cl; }
            v = valid ? acc[rt][nt][2] : -3e38f;
            if (v > b2) { s2 = b2; j2 = i2; b2 = v; i2 = cl; } else if (v > s2) { s2 = v; j2 = cl; }
            v = valid ? acc[rt][nt][3] : -3e38f;
            if (v > b3) { s3 = b3; j3 = i3; b3 = v; i3 = cl; } else if (v > s3) { s3 = v; j3 = cl; }
        }
#pragma unroll
        for (int w = 1; w <= 8; w <<= 1) {
#define MRG(B, S, I, J)                                                        \
            {                                                                  \
                float ob = __shfl_xor(B, w), os = __shfl_xor(S, w);            \
                int obi = __shfl_xor(I, w), osi = __shfl_xor(J, w);            \
                if (ob > B) {                                                  \
                    float ns; int nsi;                                         \
                    if (B > os) { ns = B; nsi = I; } else { ns = os; nsi = osi; } \
                    B = ob; I = obi; S = ns; J = nsi;                          \
                } else if (ob > S) { S = ob; J = obi; }                        \
            }
            MRG(b0, s0, i0, j0) MRG(b1, s1, i1, j1) MRG(b2, s2, i2, j2) MRG(b3, s3, i3, j3)
#undef MRG
        }
        if (l15 < 4) {
            // select reg (l15) via static names
            float bb = (l15 & 2) ? ((l15 & 1) ? b3 : b2) : ((l15 & 1) ? b1 : b0);
            float sv = (l15 & 2) ? ((l15 & 1) ? s3 : s2) : ((l15 & 1) ? s1 : s0);
            int bi   = (l15 & 2) ? ((l15 & 1) ? i3 : i2) : ((l15 & 1) ? i1 : i0);
            int si   = (l15 & 2) ? ((l15 & 1) ? j3 : j2) : ((l15 & 1) ? j1 : j0);
            int grow = rowbase + rt * 16 + rl;
            float ssr = rt ? ssr1 : ssr0;
            float nrm = fmaxf(sqrtf(ssr), EPS);
            float msim = bb / nrm;
            out_nov[grow] = 1.f - msim * msim;
            out_cls[grow] = (float)bi;
            if (bb - sv < 1e-3f * nrm) {         // near-tie: fp64 re-resolve later
                int pos = atomicAdd(flagn, 1);
                flags[pos] = ((unsigned)grow << 14) | ((unsigned)bi << 7) | (unsigned)si;
            }
        }
    }
}

// ---- cooperative fp64 refinement of flagged near-ties ----
__global__ void k_refine(const float* __restrict__ e, const float* __restrict__ c_raw,
                         const double* __restrict__ nc64, const int* __restrict__ flagn,
                         const unsigned* __restrict__ flags,
                         float* __restrict__ out_nov, float* __restrict__ out_cls) {
    int n = *flagn;
    int gw = (blockIdx.x * 256 + threadIdx.x) >> 6;
    int lane = threadIdx.x & 63;
    int nw = (gridDim.x * 256) >> 6;
    for (int i = gw; i < n; i += nw) {
        unsigned f = flags[i];
        int row = f >> 14, bi = (f >> 7) & 127, si = f & 127;
        const float* er = e + (size_t)row * D_N;
        const float* ca = c_raw + (size_t)bi * D_N;
        const float* cb = c_raw + (size_t)si * D_N;
        double d1 = 0, d2 = 0, ee = 0;
#pragma unroll
        for (int j = 0; j < 6; j++) {
            int d = lane * 6 + j;
            double ev = er[d];
            d1 += ev * (double)ca[d];
            d2 += ev * (double)cb[d];
            ee += ev * ev;
        }
#pragma unroll
        for (int w = 1; w <= 32; w <<= 1) {
            d1 += __shfl_xor(d1, w); d2 += __shfl_xor(d2, w); ee += __shfl_xor(ee, w);
        }
        if (lane == 0) {
            double v1 = d1 / nc64[bi], v2 = d2 / nc64[si];
            int k; double v;
            if (v2 > v1 || (v2 == v1 && si < bi)) { k = si; v = v2; } else { k = bi; v = v1; }
            double nrm = fmax(sqrt(ee), (double)EPS);
            double ms = v / nrm;
            out_nov[row] = (float)(1.0 - ms * ms);
            out_cls[row] = (float)k;
        }
    }
}

// ---- histogram of final assignments ----
__global__ void k_hist(const float* __restrict__ cls, int* __restrict__ cnt) {
    __shared__ int h[K_N];
    int t = threadIdx.x;
    if (t < K_N) h[t] = 0;
    __syncthreads();
    int b = blockIdx.x * 256 + t;
    atomicAdd(&h[(int)cls[b]], 1);
    __syncthreads();
    if (t < K_N && h[t] > 0) atomicAdd(&cnt[t], h[t]);
}

// ---- exclusive prefix + init cur + new_counts output ----
__global__ void k_prefix(const int* __restrict__ cnt, int* __restrict__ offs,
                         int* __restrict__ cur,
                         const float* __restrict__ counts_in, float* __restrict__ out_cnts) {
    if (threadIdx.x == 0) {
        int r = 0;
        for (int k = 0; k < K_N; k++) { offs[k] = r; cur[k] = r; r += cnt[k]; }
    }
    int t = threadIdx.x;
    if (t < K_N) out_cnts[t] = counts_in[t] + (float)cnt[t];
}

// ---- scatter row indices into cluster buckets (block-aggregated) ----
__global__ void k_scatter(const float* __restrict__ cls, int* __restrict__ cur,
                          unsigned* __restrict__ idx_buf) {
    __shared__ int h[K_N];
    __shared__ int basek[K_N];
    int t = threadIdx.x;
    if (t < K_N) h[t] = 0;
    __syncthreads();
    int b = blockIdx.x * 256 + t;
    int k = (int)cls[b];
    int lr = atomicAdd(&h[k], 1);
    __syncthreads();
    if (t < K_N && h[t] > 0) basek[t] = atomicAdd(&cur[t], h[t]);
    __syncthreads();
    idx_buf[basek[k] + lr] = (unsigned)b;
}

// ---- per-cluster segment sums (fp64 partials, 8-deep prefetch) ----
__global__ void k_segsum(const float* __restrict__ e, const unsigned* __restrict__ idx_buf,
                         const int* __restrict__ cnt, const int* __restrict__ offs,
                         double* __restrict__ partial, int seg) {
    int k = blockIdx.x, s = blockIdx.y, t = threadIdx.x;  // 384 threads
    int n = cnt[k], base = offs[k];
    int i0 = (int)((long long)n * s / seg);
    int i1 = (int)((long long)n * (s + 1) / seg);
    double a = 0.0;
    int i = i0;
    for (; i + 8 <= i1; i += 8) {
        unsigned r0 = idx_buf[base + i + 0], r1 = idx_buf[base + i + 1];
        unsigned r2 = idx_buf[base + i + 2], r3 = idx_buf[base + i + 3];
        unsigned r4 = idx_buf[base + i + 4], r5 = idx_buf[base + i + 5];
        unsigned r6 = idx_buf[base + i + 6], r7 = idx_buf[base + i + 7];
        float f0 = e[(size_t)r0 * D_N + t], f1 = e[(size_t)r1 * D_N + t];
        float f2 = e[(size_t)r2 * D_N + t], f3 = e[(size_t)r3 * D_N + t];
        float f4 = e[(size_t)r4 * D_N + t], f5 = e[(size_t)r5 * D_N + t];
        float f6 = e[(size_t)r6 * D_N + t], f7 = e[(size_t)r7 * D_N + t];
        a += (double)f0; a += (double)f1; a += (double)f2; a += (double)f3;
        a += (double)f4; a += (double)f5; a += (double)f6; a += (double)f7;
    }
    for (; i < i1; ++i)
        a += (double)e[(size_t)idx_buf[base + i] * D_N + t];
    partial[((size_t)(k * seg + s)) * D_N + t] = a;
}

// ---- finalize centroids ----
__global__ void k_final(const float* __restrict__ c_raw, const double* __restrict__ partial,
                        const int* __restrict__ cnt, float* __restrict__ out_cent, int seg) {
    int idx = blockIdx.x * 256 + threadIdx.x;
    if (idx >= K_N * D_N) return;
    int k = idx / D_N;
    int d = idx - k * D_N;
    double sum = 0.0;
    for (int s = 0; s < seg; s++) sum += partial[((size_t)(k * seg + s)) * D_N + d];
    int n = cnt[k];
    float c0 = c_raw[idx];
    float mean = (float)(sum / (double)(n > 1 ? n : 1));
    out_cent[idx] = (n > 0) ? (MOM * c0 + (1.0f - MOM) * mean) : c0;
}

extern "C" void kernel_launch(void* const* d_in, const int* in_sizes, int n_in,
                              void* d_out, int out_size, void* d_ws, size_t ws_size,
                              hipStream_t stream) {
    const float* emb    = (const float*)d_in[0];
    const float* cen    = (const float*)d_in[1];
    const float* counts = (const float*)d_in[2];
    float* out = (float*)d_out;
    char* ws = (char*)d_ws;

    unsigned short* chi     = (unsigned short*)(ws + OFF_CHI);
    unsigned short* clo     = (unsigned short*)(ws + OFF_CLO);
    double*         nc64    = (double*)(ws + OFF_NC64);
    int*            cnt     = (int*)(ws + OFF_CNT);
    int*            offs    = (int*)(ws + OFF_OFFS);
    int*            cur     = (int*)(ws + OFF_CUR);
    int*            flagn   = (int*)(ws + OFF_FLAGN);
    unsigned*       flags   = (unsigned*)(ws + OFF_FLAGS);
    unsigned*       idx_buf = (unsigned*)(ws + OFF_IDX);
    double*         partial = (double*)(ws + OFF_PART);

    int seg = SEG_MAX;
    while (seg > 1 && OFF_PART + (size_t)K_N * seg * D_N * 8 > ws_size) seg >>= 1;

    float* out_nov  = out;
    float* out_cls  = out + B_N;
    float* out_cent = out + 2 * B_N;
    float* out_cnts = out + 2 * B_N + K_N * D_N;

    k_norm_c<<<NPAD, 128, 0, stream>>>(cen, chi, clo, nc64);
    k_zero<<<1, 128, 0, stream>>>(cnt, flagn);
    k_main<<<B_N / 128, 256, 0, stream>>>(emb, chi, clo, out_nov, out_cls, flags, flagn);
    k_refine<<<256, 256, 0, stream>>>(emb, cen, nc64, flagn, flags, out_nov, out_cls);
    k_hist<<<B_N / 256, 256, 0, stream>>>(out_cls, cnt);
    k_prefix<<<1, 128, 0, stream>>>(cnt, offs, cur, counts, out_cnts);
    k_scatter<<<B_N / 256, 256, 0, stream>>>(out_cls, cur, idx_buf);
    k_segsum<<<dim3(K_N, seg), 384, 0, stream>>>(emb, idx_buf, cnt, offs, partial, seg);
    k_final<<<(K_N * D_N + 255) / 256, 256, 0, stream>>>(cen, partial, cnt, out_cent, seg);
}

// Round 4
// 351.998 us; speedup vs baseline: 5.4328x; 1.1431x over previous
//
#include <hip/hip_runtime.h>
#include <math.h>

#define B_N 262144
#define K_N 100
#define NPAD 112
#define D_N 384
#define EPS 1e-8f
#define MOM 0.95f
#define SEG_MAX 32

typedef __attribute__((ext_vector_type(8))) short short8;
typedef __attribute__((ext_vector_type(4))) float f32x4;

// workspace byte offsets
#define OFF_CPK   0          // 12*14336 = 172032 B : B packed [kk][tile14][1KB]
#define OFF_NC64  172032     // K f64
#define OFF_CNT   172864
#define OFF_OFFS  173312
#define OFF_CUR   173760
#define OFF_FLAGN 174208
#define OFF_FLAGS 174272     // B u32 = 1048576
#define OFF_IDX   1222848    // B u32 = 1048576
#define OFF_PART  2271424    // K*seg*D f64

#define GLOAD_LDS(g, l) __builtin_amdgcn_global_load_lds( \
    (const __attribute__((address_space(1))) unsigned int*)(g), \
    (__attribute__((address_space(3))) unsigned int*)(l), 16, 0, 0)

// cpk u16 index for element (col, d) half h (0=hi,1=lo)
__device__ __forceinline__ size_t cpk_idx(int col, int d, int h) {
    int kk = d >> 5, r = d & 31, lg = r >> 3, j = r & 7;
    int nt = col >> 4, l15 = col & 15;
    return (size_t)((kk * 14 + nt * 2 + h) * 512) + lg * 128 + l15 * 8 + j;
}

// ---- normalize centroids -> bf16 hi/lo split into MFMA-fragment-ordered cpk ----
__global__ void k_norm_c(const float* __restrict__ c, unsigned short* __restrict__ cpk,
                         double* __restrict__ nc64) {
    int col = blockIdx.x;
    int t = threadIdx.x;  // 128
    if (col >= K_N) {
        for (int d = t; d < D_N; d += 128) {
            cpk[cpk_idx(col, d, 0)] = 0; cpk[cpk_idx(col, d, 1)] = 0;
        }
        return;
    }
    const float* row = c + (size_t)col * D_N;
    double ss = 0.0;
    for (int d = t; d < D_N; d += 128) { double v = row[d]; ss += v * v; }
    __shared__ double red[2];
    for (int o = 32; o > 0; o >>= 1) ss += __shfl_down(ss, o);
    if ((t & 63) == 0) red[t >> 6] = ss;
    __syncthreads();
    double nc = fmax(sqrt(red[0] + red[1]), (double)EPS);
    if (t == 0) nc64[col] = nc;
    float inv = (float)(1.0 / nc);
    for (int d = t; d < D_N; d += 128) {
        float x = row[d] * inv;
        unsigned xb = __float_as_uint(x);
        unsigned hb = xb & 0xffff0000u;
        float lf = x - __uint_as_float(hb);
        cpk[cpk_idx(col, d, 0)] = (unsigned short)(hb >> 16);
        cpk[cpk_idx(col, d, 1)] = (unsigned short)(__float_as_uint(lf) >> 16);
    }
}

__global__ void k_zero(int* cnt, int* flagn) {
    int t = threadIdx.x;
    if (t < K_N) cnt[t] = 0;
    if (t == 0) *flagn = 0;
}

__device__ __forceinline__ void splitA(float4 x0, float4 x1,
                                       short8& ah, short8& al, float& ss) {
    float xs[8] = {x0.x, x0.y, x0.z, x0.w, x1.x, x1.y, x1.z, x1.w};
#pragma unroll
    for (int j = 0; j < 8; j++) {
        float x = xs[j];
        unsigned xb = __float_as_uint(x);
        unsigned hb = xb & 0xffff0000u;
        float lf = x - __uint_as_float(hb);
        ah[j] = (short)(hb >> 16);
        al[j] = (short)(__float_as_uint(lf) >> 16);
        ss = fmaf(x, x, ss);
    }
}

// ---- MFMA sims, LDS-staged B (double-buffered), reg-double-buffered A ----
__global__ __launch_bounds__(256) void k_main(
    const float* __restrict__ e, const unsigned short* __restrict__ cpk,
    float* __restrict__ out_nov, float* __restrict__ out_cls,
    unsigned* __restrict__ flags, int* __restrict__ flagn) {
    __shared__ unsigned short sB[2 * 7168];   // 2 x 14336 B
    const int t = threadIdx.x;
    const int lane = t & 63;
    const int wid = t >> 6;
    const int l15 = lane & 15;
    const int lg = lane >> 4;
    const int rowbase = blockIdx.x * 128 + wid * 32;

    const float* a0p = e + (size_t)(rowbase + l15) * D_N + lg * 8;
    const float* a1p = a0p + (size_t)16 * D_N;

    f32x4 acc[2][7];
#pragma unroll
    for (int rt = 0; rt < 2; rt++)
#pragma unroll
        for (int nt = 0; nt < 7; nt++) acc[rt][nt] = f32x4{0.f, 0.f, 0.f, 0.f};

    float ss0 = 0.f, ss1 = 0.f;
    float4 a[2][4];

    // prologue: stage B(0), load A(0)
#pragma unroll
    for (int t4 = 0; t4 < 4; t4++) {
        int tile = wid + 4 * t4;
        if (tile < 14)
            GLOAD_LDS((const char*)cpk + tile * 1024 + lane * 16,
                      (char*)sB + tile * 1024);
    }
    a[0][0] = *(const float4*)(a0p);
    a[0][1] = *(const float4*)(a0p + 4);
    a[0][2] = *(const float4*)(a1p);
    a[0][3] = *(const float4*)(a1p + 4);
    __syncthreads();

#pragma unroll
    for (int kk = 0; kk < 12; kk++) {
        const int par = kk & 1;
        if (kk < 11) {
            // stage B(kk+1) into other buffer; load A(kk+1) into other regs
#pragma unroll
            for (int t4 = 0; t4 < 4; t4++) {
                int tile = wid + 4 * t4;
                if (tile < 14)
                    GLOAD_LDS((const char*)cpk + (size_t)(kk + 1) * 14336 + tile * 1024 + lane * 16,
                              (char*)sB + (par ^ 1) * 14336 + tile * 1024);
            }
            const int ko = (kk + 1) * 32;
            a[par ^ 1][0] = *(const float4*)(a0p + ko);
            a[par ^ 1][1] = *(const float4*)(a0p + ko + 4);
            a[par ^ 1][2] = *(const float4*)(a1p + ko);
            a[par ^ 1][3] = *(const float4*)(a1p + ko + 4);
        }

        short8 ah0, al0, ah1, al1;
        splitA(a[par][0], a[par][1], ah0, al0, ss0);
        splitA(a[par][2], a[par][3], ah1, al1, ss1);

        const unsigned short* bb = sB + par * 7168;
#pragma unroll
        for (int nt = 0; nt < 7; nt++) {
            short8 bh = *(const short8*)(bb + nt * 1024 + lane * 8);
            short8 bl = *(const short8*)(bb + nt * 1024 + 512 + lane * 8);
            acc[0][nt] = __builtin_amdgcn_mfma_f32_16x16x32_bf16(ah0, bh, acc[0][nt], 0, 0, 0);
            acc[0][nt] = __builtin_amdgcn_mfma_f32_16x16x32_bf16(al0, bh, acc[0][nt], 0, 0, 0);
            acc[0][nt] = __builtin_amdgcn_mfma_f32_16x16x32_bf16(ah0, bl, acc[0][nt], 0, 0, 0);
            acc[1][nt] = __builtin_amdgcn_mfma_f32_16x16x32_bf16(ah1, bh, acc[1][nt], 0, 0, 0);
            acc[1][nt] = __builtin_amdgcn_mfma_f32_16x16x32_bf16(al1, bh, acc[1][nt], 0, 0, 0);
            acc[1][nt] = __builtin_amdgcn_mfma_f32_16x16x32_bf16(ah1, bl, acc[1][nt], 0, 0, 0);
        }
        __syncthreads();   // drains this wave's DMA (vmcnt0) + block barrier
    }

    // row sum-of-squares
    ss0 += __shfl_xor(ss0, 16); ss0 += __shfl_xor(ss0, 32);
    ss1 += __shfl_xor(ss1, 16); ss1 += __shfl_xor(ss1, 32);
    const int rl = lg * 4 + (l15 & 3);
    float ssr0 = __shfl(ss0, rl);
    float ssr1 = __shfl(ss1, rl);

#pragma unroll
    for (int rt = 0; rt < 2; rt++) {
        float b0 = -3e38f, b1 = -3e38f, b2 = -3e38f, b3 = -3e38f;
        float s0 = -3e38f, s1 = -3e38f, s2 = -3e38f, s3 = -3e38f;
        int i0 = 0, i1 = 0, i2 = 0, i3 = 0, j0 = 0, j1 = 0, j2 = 0, j3 = 0;
#pragma unroll
        for (int nt = 0; nt < 7; nt++) {
            int cl = nt * 16 + l15;
            bool valid = cl < K_N;
            float v;
            v = valid ? acc[rt][nt][0] : -3e38f;
            if (v > b0) { s0 = b0; j0 = i0; b0 = v; i0 = cl; } else if (v > s0) { s0 = v; j0 = cl; }
            v = valid ? acc[rt][nt][1] : -3e38f;
            if (v > b1) { s1 = b1; j1 = i1; b1 = v; i1 = cl; } else if (v > s1) { s1 = v; j1 = cl; }
            v = valid ? acc[rt][nt][2] : -3e38f;
            if (v > b2) { s2 = b2; j2 = i2; b2 = v; i2 = cl; } else if (v > s2) { s2 = v; j2 = cl; }
            v = valid ? acc[rt][nt][3] : -3e38f;
            if (v > b3) { s3 = b3; j3 = i3; b3 = v; i3 = cl; } else if (v > s3) { s3 = v; j3 = cl; }
        }
#pragma unroll
        for (int w = 1; w <= 8; w <<= 1) {
#define MRG(B, S, I, J)                                                        \
            {                                                                  \
                float ob = __shfl_xor(B, w), os = __shfl_xor(S, w);            \
                int obi = __shfl_xor(I, w), osi = __shfl_xor(J, w);            \
                if (ob > B) {                                                  \
                    float ns; int nsi;                                         \
                    if (B > os) { ns = B; nsi = I; } else { ns = os; nsi = osi; } \
                    B = ob; I = obi; S = ns; J = nsi;                          \
                } else if (ob > S) { S = ob; J = obi; }                        \
            }
            MRG(b0, s0, i0, j0) MRG(b1, s1, i1, j1) MRG(b2, s2, i2, j2) MRG(b3, s3, i3, j3)
#undef MRG
        }
        if (l15 < 4) {
            float bb = (l15 & 2) ? ((l15 & 1) ? b3 : b2) : ((l15 & 1) ? b1 : b0);
            float sv = (l15 & 2) ? ((l15 & 1) ? s3 : s2) : ((l15 & 1) ? s1 : s0);
            int bi   = (l15 & 2) ? ((l15 & 1) ? i3 : i2) : ((l15 & 1) ? i1 : i0);
            int si   = (l15 & 2) ? ((l15 & 1) ? j3 : j2) : ((l15 & 1) ? j1 : j0);
            int grow = rowbase + rt * 16 + rl;
            float ssr = rt ? ssr1 : ssr0;
            float nrm = fmaxf(sqrtf(ssr), EPS);
            float msim = bb / nrm;
            out_nov[grow] = 1.f - msim * msim;
            out_cls[grow] = (float)bi;
            if (bb - sv < 1e-3f * nrm) {
                int pos = atomicAdd(flagn, 1);
                flags[pos] = ((unsigned)grow << 14) | ((unsigned)bi << 7) | (unsigned)si;
            }
        }
    }
}

// ---- cooperative fp64 refinement of flagged near-ties ----
__global__ void k_refine(const float* __restrict__ e, const float* __restrict__ c_raw,
                         const double* __restrict__ nc64, const int* __restrict__ flagn,
                         const unsigned* __restrict__ flags,
                         float* __restrict__ out_nov, float* __restrict__ out_cls) {
    int n = *flagn;
    int gw = (blockIdx.x * 256 + threadIdx.x) >> 6;
    int lane = threadIdx.x & 63;
    int nw = (gridDim.x * 256) >> 6;
    for (int i = gw; i < n; i += nw) {
        unsigned f = flags[i];
        int row = f >> 14, bi = (f >> 7) & 127, si = f & 127;
        const float* er = e + (size_t)row * D_N;
        const float* ca = c_raw + (size_t)bi * D_N;
        const float* cb = c_raw + (size_t)si * D_N;
        double d1 = 0, d2 = 0, ee = 0;
#pragma unroll
        for (int j = 0; j < 6; j++) {
            int d = lane * 6 + j;
            double ev = er[d];
            d1 += ev * (double)ca[d];
            d2 += ev * (double)cb[d];
            ee += ev * ev;
        }
#pragma unroll
        for (int w = 1; w <= 32; w <<= 1) {
            d1 += __shfl_xor(d1, w); d2 += __shfl_xor(d2, w); ee += __shfl_xor(ee, w);
        }
        if (lane == 0) {
            double v1 = d1 / nc64[bi], v2 = d2 / nc64[si];
            int k; double v;
            if (v2 > v1 || (v2 == v1 && si < bi)) { k = si; v = v2; } else { k = bi; v = v1; }
            double nrm = fmax(sqrt(ee), (double)EPS);
            double ms = v / nrm;
            out_nov[row] = (float)(1.0 - ms * ms);
            out_cls[row] = (float)k;
        }
    }
}

__global__ void k_hist(const float* __restrict__ cls, int* __restrict__ cnt) {
    __shared__ int h[K_N];
    int t = threadIdx.x;
    if (t < K_N) h[t] = 0;
    __syncthreads();
    int b = blockIdx.x * 256 + t;
    atomicAdd(&h[(int)cls[b]], 1);
    __syncthreads();
    if (t < K_N && h[t] > 0) atomicAdd(&cnt[t], h[t]);
}

__global__ void k_prefix(const int* __restrict__ cnt, int* __restrict__ offs,
                         int* __restrict__ cur,
                         const float* __restrict__ counts_in, float* __restrict__ out_cnts) {
    if (threadIdx.x == 0) {
        int r = 0;
        for (int k = 0; k < K_N; k++) { offs[k] = r; cur[k] = r; r += cnt[k]; }
    }
    int t = threadIdx.x;
    if (t < K_N) out_cnts[t] = counts_in[t] + (float)cnt[t];
}

__global__ void k_scatter(const float* __restrict__ cls, int* __restrict__ cur,
                          unsigned* __restrict__ idx_buf) {
    __shared__ int h[K_N];
    __shared__ int basek[K_N];
    int t = threadIdx.x;
    if (t < K_N) h[t] = 0;
    __syncthreads();
    int b = blockIdx.x * 256 + t;
    int k = (int)cls[b];
    int lr = atomicAdd(&h[k], 1);
    __syncthreads();
    if (t < K_N && h[t] > 0) basek[t] = atomicAdd(&cur[t], h[t]);
    __syncthreads();
    idx_buf[basek[k] + lr] = (unsigned)b;
}

// ---- per-cluster segment sums: float4 loads, 4 rows in flight, LDS reduce ----
__global__ void k_segsum(const float* __restrict__ e, const unsigned* __restrict__ idx_buf,
                         const int* __restrict__ cnt, const int* __restrict__ offs,
                         double* __restrict__ partial, int seg) {
    __shared__ double red[3][96][4];
    int k = blockIdx.x, s = blockIdx.y, t = threadIdx.x;   // 384 threads
    int r4 = t / 96, c4 = t - r4 * 96;
    int n = cnt[k], base = offs[k];
    int i0 = (int)((long long)n * s / seg);
    int i1 = (int)((long long)n * (s + 1) / seg);
    double a0 = 0, a1 = 0, a2 = 0, a3 = 0;
    int i = i0 + r4;
    unsigned rn = (i < i1) ? idx_buf[base + i] : 0u;
    while (i < i1) {
        unsigned r = rn;
        int inext = i + 4;
        rn = (inext < i1) ? idx_buf[base + inext] : 0u;
        float4 v = *(const float4*)(e + (size_t)r * D_N + c4 * 4);
        a0 += v.x; a1 += v.y; a2 += v.z; a3 += v.w;
        i = inext;
    }
    if (r4 > 0) {
        red[r4 - 1][c4][0] = a0; red[r4 - 1][c4][1] = a1;
        red[r4 - 1][c4][2] = a2; red[r4 - 1][c4][3] = a3;
    }
    __syncthreads();
    if (r4 == 0) {
        a0 += red[0][c4][0] + red[1][c4][0] + red[2][c4][0];
        a1 += red[0][c4][1] + red[1][c4][1] + red[2][c4][1];
        a2 += red[0][c4][2] + red[1][c4][2] + red[2][c4][2];
        a3 += red[0][c4][3] + red[1][c4][3] + red[2][c4][3];
        double* p = partial + ((size_t)(k * seg + s)) * D_N + c4 * 4;
        p[0] = a0; p[1] = a1; p[2] = a2; p[3] = a3;
    }
}

__global__ void k_final(const float* __restrict__ c_raw, const double* __restrict__ partial,
                        const int* __restrict__ cnt, float* __restrict__ out_cent, int seg) {
    int idx = blockIdx.x * 256 + threadIdx.x;
    if (idx >= K_N * D_N) return;
    int k = idx / D_N;
    int d = idx - k * D_N;
    double sum = 0.0;
    for (int s = 0; s < seg; s++) sum += partial[((size_t)(k * seg + s)) * D_N + d];
    int n = cnt[k];
    float c0 = c_raw[idx];
    float mean = (float)(sum / (double)(n > 1 ? n : 1));
    out_cent[idx] = (n > 0) ? (MOM * c0 + (1.0f - MOM) * mean) : c0;
}

extern "C" void kernel_launch(void* const* d_in, const int* in_sizes, int n_in,
                              void* d_out, int out_size, void* d_ws, size_t ws_size,
                              hipStream_t stream) {
    const float* emb    = (const float*)d_in[0];
    const float* cen    = (const float*)d_in[1];
    const float* counts = (const float*)d_in[2];
    float* out = (float*)d_out;
    char* ws = (char*)d_ws;

    unsigned short* cpk     = (unsigned short*)(ws + OFF_CPK);
    double*         nc64    = (double*)(ws + OFF_NC64);
    int*            cnt     = (int*)(ws + OFF_CNT);
    int*            offs    = (int*)(ws + OFF_OFFS);
    int*            cur     = (int*)(ws + OFF_CUR);
    int*            flagn   = (int*)(ws + OFF_FLAGN);
    unsigned*       flags   = (unsigned*)(ws + OFF_FLAGS);
    unsigned*       idx_buf = (unsigned*)(ws + OFF_IDX);
    double*         partial = (double*)(ws + OFF_PART);

    int seg = SEG_MAX;
    while (seg > 1 && OFF_PART + (size_t)K_N * seg * D_N * 8 > ws_size) seg >>= 1;

    float* out_nov  = out;
    float* out_cls  = out + B_N;
    float* out_cent = out + 2 * B_N;
    float* out_cnts = out + 2 * B_N + K_N * D_N;

    k_norm_c<<<NPAD, 128, 0, stream>>>(cen, cpk, nc64);
    k_zero<<<1, 128, 0, stream>>>(cnt, flagn);
    k_main<<<B_N / 128, 256, 0, stream>>>(emb, cpk, out_nov, out_cls, flags, flagn);
    k_refine<<<256, 256, 0, stream>>>(emb, cen, nc64, flagn, flags, out_nov, out_cls);
    k_hist<<<B_N / 256, 256, 0, stream>>>(out_cls, cnt);
    k_prefix<<<1, 128, 0, stream>>>(cnt, offs, cur, counts, out_cnts);
    k_scatter<<<B_N / 256, 256, 0, stream>>>(out_cls, cur, idx_buf);
    k_segsum<<<dim3(K_N, seg), 384, 0, stream>>>(emb, idx_buf, cnt, offs, partial, seg);
    k_final<<<(K_N * D_N + 255) / 256, 256, 0, stream>>>(cen, partial, cnt, out_cent, seg);
}